// Round 1
// baseline (3172.287 us; speedup 1.0000x reference)
//
#include <hip/hip_runtime.h>

#define NN 100000
#define EE 1600000
#define HH 128
#define MM 256
#define LL 6
#define GG 512
#define SCAN_NB ((NN + 1023) / 1024)

__device__ __forceinline__ float swishf(float v) {
    return v / (1.0f + __expf(-v));
}

// h[n,c] = z_embed[z[n],c] + sum_j x[n,1+j]*extra_w[c,j] + extra_b[c]
__global__ void k_embed(const float* __restrict__ x, const float* __restrict__ z_embed,
                        const float* __restrict__ ew, const float* __restrict__ eb,
                        float* __restrict__ h) {
    int idx = blockIdx.x * blockDim.x + threadIdx.x;
    if (idx >= NN * 32) return;
    int n = idx >> 5;
    int c0 = (idx & 31) << 2;
    const float* xr = x + (size_t)n * 4;
    int z = (int)xr[0];
    float x1 = xr[1], x2 = xr[2], x3 = xr[3];
    const float* ze = z_embed + (size_t)z * HH + c0;
    float o[4];
#pragma unroll
    for (int j = 0; j < 4; ++j) {
        int c = c0 + j;
        o[j] = ze[j] + x1 * ew[c * 3 + 0] + x2 * ew[c * 3 + 1] + x3 * ew[c * 3 + 2] + eb[c];
    }
    *(float4*)(h + (size_t)n * HH + c0) = make_float4(o[0], o[1], o[2], o[3]);
}

__global__ void k_degree(const int* __restrict__ dst, int* __restrict__ deg) {
    int e = blockIdx.x * blockDim.x + threadIdx.x;
    if (e < EE) atomicAdd(&deg[dst[e]], 1);
}

__global__ void k_dinv(const int* __restrict__ deg, float* __restrict__ dinv) {
    int n = blockIdx.x * blockDim.x + threadIdx.x;
    if (n < NN) dinv[n] = rsqrtf((float)(deg[n] + 1));
}

__global__ void k_scan1(const int* __restrict__ deg, int* __restrict__ bsum) {
    __shared__ int sd[256];
    int t = threadIdx.x;
    int base = blockIdx.x * 1024 + t * 4;
    int s = 0;
#pragma unroll
    for (int j = 0; j < 4; ++j) {
        int i = base + j;
        if (i < NN) s += deg[i];
    }
    sd[t] = s;
    __syncthreads();
    for (int off = 128; off > 0; off >>= 1) {
        if (t < off) sd[t] += sd[t + off];
        __syncthreads();
    }
    if (t == 0) bsum[blockIdx.x] = sd[0];
}

__global__ void k_scan2(const int* __restrict__ bsum, int* __restrict__ boff) {
    __shared__ int sd[128];
    int t = threadIdx.x;
    int v = (t < SCAN_NB) ? bsum[t] : 0;
    sd[t] = v;
    __syncthreads();
    for (int off = 1; off < 128; off <<= 1) {
        int u = (t >= off) ? sd[t - off] : 0;
        __syncthreads();
        sd[t] += u;
        __syncthreads();
    }
    boff[t] = sd[t] - v;  // exclusive
}

__global__ void k_scan3(const int* __restrict__ deg, const int* __restrict__ boff,
                        int* __restrict__ rowptr) {
    __shared__ int sd[256];
    int t = threadIdx.x;
    int base = blockIdx.x * 1024 + t * 4;
    int v[4];
    int s = 0;
#pragma unroll
    for (int j = 0; j < 4; ++j) {
        int i = base + j;
        v[j] = (i < NN) ? deg[i] : 0;
        s += v[j];
    }
    sd[t] = s;
    __syncthreads();
    for (int off = 1; off < 256; off <<= 1) {
        int u = (t >= off) ? sd[t - off] : 0;
        __syncthreads();
        sd[t] += u;
        __syncthreads();
    }
    int run = boff[blockIdx.x] + sd[t] - s;
#pragma unroll
    for (int j = 0; j < 4; ++j) {
        int i = base + j;
        if (i < NN) rowptr[i] = run;
        if (i == NN - 1) rowptr[NN] = run + v[j];
        run += v[j];
    }
}

__global__ void k_fill(const int* __restrict__ ei, const int* __restrict__ rowptr,
                       int* __restrict__ cursor, int* __restrict__ col) {
    int e = blockIdx.x * blockDim.x + threadIdx.x;
    if (e >= EE) return;
    int s = ei[e];
    int d = ei[EE + e];
    int p = atomicAdd(&cursor[d], 1);
    col[rowptr[d] + p] = s;
}

__global__ void k_gptr(const int* __restrict__ batch, int* __restrict__ gptr) {
    int n = blockIdx.x * blockDim.x + threadIdx.x;
    if (n >= NN) return;
    int b = batch[n];
    int pb = (n == 0) ? -1 : batch[n - 1];
    for (int g = pb + 1; g <= b; ++g) gptr[g] = n;
    if (n == NN - 1) {
        for (int g = b + 1; g <= GG; ++g) gptr[g] = NN;
    }
}

// C[N,Cout] = A[N,K] @ B[Cout,K]^T  (+ epilogue)
// EPI 0: C = acc * dinv[row]          (aux = dinv)
// EPI 1: C = swish(acc + bias)
// EPI 2: C = swish(acc + bias) + res  (aux = residual, Cout==HH)
template <int EPI>
__global__ __launch_bounds__(256) void k_gemm(const float* __restrict__ A,
                                              const float* __restrict__ B,
                                              const float* __restrict__ bias,
                                              const float* aux, float* C, int K, int Cout) {
    __shared__ float As[16][132];
    __shared__ float Bs[16][132];
    const int tid = threadIdx.x;
    const int rowBase = blockIdx.x * 128;
    const int colBase = blockIdx.y * 128;
    const int tr = tid >> 2;
    const int tk = (tid & 3) << 2;
    const int icol = tid & 15;
    const int jrow = tid >> 4;

    float acc[8][8];
#pragma unroll
    for (int i = 0; i < 8; ++i)
#pragma unroll
        for (int j = 0; j < 8; ++j) acc[i][j] = 0.0f;

    for (int k0 = 0; k0 < K; k0 += 16) {
#pragma unroll
        for (int l = 0; l < 2; ++l) {
            int m = tr + (l << 6);
            int r = rowBase + m;
            float4 va = make_float4(0.f, 0.f, 0.f, 0.f);
            if (r < NN) va = *(const float4*)(A + (size_t)r * K + k0 + tk);
            As[tk + 0][m] = va.x;
            As[tk + 1][m] = va.y;
            As[tk + 2][m] = va.z;
            As[tk + 3][m] = va.w;
            float4 vb = *(const float4*)(B + (size_t)(colBase + m) * K + k0 + tk);
            Bs[tk + 0][m] = vb.x;
            Bs[tk + 1][m] = vb.y;
            Bs[tk + 2][m] = vb.z;
            Bs[tk + 3][m] = vb.w;
        }
        __syncthreads();
#pragma unroll
        for (int kk = 0; kk < 16; ++kk) {
            float4 a0 = *(const float4*)(&As[kk][jrow * 8]);
            float4 a1 = *(const float4*)(&As[kk][jrow * 8 + 4]);
            float4 b0 = *(const float4*)(&Bs[kk][icol * 8]);
            float4 b1 = *(const float4*)(&Bs[kk][icol * 8 + 4]);
            float a[8] = {a0.x, a0.y, a0.z, a0.w, a1.x, a1.y, a1.z, a1.w};
            float b[8] = {b0.x, b0.y, b0.z, b0.w, b1.x, b1.y, b1.z, b1.w};
#pragma unroll
            for (int i = 0; i < 8; ++i)
#pragma unroll
                for (int j = 0; j < 8; ++j) acc[i][j] = __builtin_fmaf(a[i], b[j], acc[i][j]);
        }
        __syncthreads();
    }

    float bv[8];
    if (EPI >= 1) {
#pragma unroll
        for (int j = 0; j < 8; ++j) bv[j] = bias[colBase + icol * 8 + j];
    }
#pragma unroll
    for (int rr = 0; rr < 8; ++rr) {
        int r = rowBase + jrow * 8 + rr;
        if (r < NN) {
            float o[8];
            if (EPI == 0) {
                float dv = aux[r];
#pragma unroll
                for (int j = 0; j < 8; ++j) o[j] = acc[rr][j] * dv;
            } else if (EPI == 1) {
#pragma unroll
                for (int j = 0; j < 8; ++j) o[j] = swishf(acc[rr][j] + bv[j]);
            } else {
                const float* res = aux + (size_t)r * HH + colBase + icol * 8;
#pragma unroll
                for (int j = 0; j < 8; ++j) o[j] = swishf(acc[rr][j] + bv[j]) + res[j];
            }
            float* cp = C + (size_t)r * Cout + colBase + icol * 8;
            *(float4*)cp = make_float4(o[0], o[1], o[2], o[3]);
            *(float4*)(cp + 4) = make_float4(o[4], o[5], o[6], o[7]);
        }
    }
}

// agg[d] = dinv[d] * (sum_{s in in(d)} y[s] + y[d]) + conv_b   (y pre-scaled by dinv[src])
__global__ __launch_bounds__(256) void k_agg(const float* __restrict__ y,
                                             const int* __restrict__ rowptr,
                                             const int* __restrict__ col,
                                             const float* __restrict__ dinv,
                                             const float* __restrict__ cb,
                                             float* __restrict__ agg) {
    int w = threadIdx.x >> 6;
    int lane = threadIdx.x & 63;
    int d = blockIdx.x * 4 + w;
    if (d >= NN) return;
    int c = lane << 1;
    const float2* yv = (const float2*)y;
    size_t selfIdx = ((size_t)d * HH + c) >> 1;
    float2 acc = yv[selfIdx];
    int beg = rowptr[d];
    int end = rowptr[d + 1];
    int e = beg;
    for (; e + 1 < end; e += 2) {
        int s0 = col[e];
        int s1 = col[e + 1];
        float2 v0 = yv[((size_t)s0 * HH + c) >> 1];
        float2 v1 = yv[((size_t)s1 * HH + c) >> 1];
        acc.x += v0.x + v1.x;
        acc.y += v0.y + v1.y;
    }
    if (e < end) {
        int s0 = col[e];
        float2 v0 = yv[((size_t)s0 * HH + c) >> 1];
        acc.x += v0.x;
        acc.y += v0.y;
    }
    float dv = dinv[d];
    agg[(size_t)d * HH + c] = acc.x * dv + cb[c];
    agg[(size_t)d * HH + c + 1] = acc.y * dv + cb[c + 1];
}

// per-graph mean/rstd; var = E[a^2] - ms*(2-ms)*mean^2
__global__ __launch_bounds__(128) void k_stats(const float* __restrict__ agg,
                                               const int* __restrict__ gptr,
                                               const float* __restrict__ ms,
                                               float* __restrict__ gmean,
                                               float* __restrict__ grstd) {
    int g = blockIdx.x;
    int c = threadIdx.x;
    int beg = gptr[g];
    int end = gptr[g + 1];
    float S1 = 0.f, S2 = 0.f;
    for (int n = beg; n < end; ++n) {
        float v = agg[(size_t)n * HH + c];
        S1 += v;
        S2 += v * v;
    }
    int cnt = end - beg;
    float inv = 1.0f / (float)(cnt > 0 ? cnt : 1);
    float m = S1 * inv;
    float msc = ms[c];
    float var = S2 * inv - msc * (2.0f - msc) * m * m;
    gmean[g * HH + c] = m;
    grstd[g * HH + c] = rsqrtf(var + 1e-5f);
}

__global__ void k_normswish(const float* __restrict__ agg, const int* __restrict__ batch,
                            const float* __restrict__ gamma, const float* __restrict__ beta,
                            const float* __restrict__ ms, const float* __restrict__ gmean,
                            const float* __restrict__ grstd, float* __restrict__ ha) {
    int idx = blockIdx.x * blockDim.x + threadIdx.x;
    if (idx >= NN * 32) return;
    int n = idx >> 5;
    int c0 = (idx & 31) << 2;
    int g = batch[n];
    float4 a = *(const float4*)(agg + (size_t)n * HH + c0);
    float av[4] = {a.x, a.y, a.z, a.w};
    float o[4];
#pragma unroll
    for (int j = 0; j < 4; ++j) {
        int c = c0 + j;
        float sub = av[j] - ms[c] * gmean[g * HH + c];
        float hn = gamma[c] * sub * grstd[g * HH + c] + beta[c];
        o[j] = swishf(hn);
    }
    *(float4*)(ha + (size_t)n * HH + c0) = make_float4(o[0], o[1], o[2], o[3]);
}

extern "C" void kernel_launch(void* const* d_in, const int* in_sizes, int n_in,
                              void* d_out, int out_size, void* d_ws, size_t ws_size,
                              hipStream_t stream) {
    const float* x = (const float*)d_in[0];
    const int* ei = (const int*)d_in[1];
    const int* batch = (const int*)d_in[2];
    const float* z_embed = (const float*)d_in[3];
    const float* extra_w = (const float*)d_in[4];
    const float* extra_b = (const float*)d_in[5];
    const float* conv_w = (const float*)d_in[6];
    const float* conv_b = (const float*)d_in[7];
    const float* gamma = (const float*)d_in[8];
    const float* beta = (const float*)d_in[9];
    const float* mean_scale = (const float*)d_in[10];
    const float* mlp_w1 = (const float*)d_in[11];
    const float* mlp_b1 = (const float*)d_in[12];
    const float* mlp_w2 = (const float*)d_in[13];
    const float* mlp_b2 = (const float*)d_in[14];
    float* h = (float*)d_out;

    char* wsB = (char*)d_ws;
    size_t off = 0;
    auto alloc = [&](size_t bytes) -> void* {
        void* p = (void*)(wsB + off);
        off = (off + bytes + 255) & ~(size_t)255;
        return p;
    };
    float* dinv = (float*)alloc((size_t)NN * 4);
    int* deg = (int*)alloc((size_t)NN * 4);
    int* cursor = (int*)alloc((size_t)NN * 4);
    int* rowptr = (int*)alloc((size_t)(NN + 1) * 4);
    int* bsum = (int*)alloc(128 * 4);
    int* boff = (int*)alloc(128 * 4);
    int* col = (int*)alloc((size_t)EE * 4);
    int* gptr = (int*)alloc((size_t)(GG + 1) * 4);
    float* gmean = (float*)alloc((size_t)GG * HH * 4);
    float* grstd = (float*)alloc((size_t)GG * HH * 4);
    float* y = (float*)alloc((size_t)NN * HH * 4);
    float* aggt = (float*)alloc((size_t)NN * MM * 4);  // first NN*HH = agg, whole = t
    float* agg = aggt;
    float* t = aggt;

    hipMemsetAsync(deg, 0, (size_t)NN * 4, stream);
    hipMemsetAsync(cursor, 0, (size_t)NN * 4, stream);

    k_embed<<<(NN * 32 + 255) / 256, 256, 0, stream>>>(x, z_embed, extra_w, extra_b, h);
    k_degree<<<(EE + 255) / 256, 256, 0, stream>>>(ei + EE, deg);
    k_dinv<<<(NN + 255) / 256, 256, 0, stream>>>(deg, dinv);
    k_scan1<<<SCAN_NB, 256, 0, stream>>>(deg, bsum);
    k_scan2<<<1, 128, 0, stream>>>(bsum, boff);
    k_scan3<<<SCAN_NB, 256, 0, stream>>>(deg, boff, rowptr);
    k_fill<<<(EE + 255) / 256, 256, 0, stream>>>(ei, rowptr, cursor, col);
    k_gptr<<<(NN + 255) / 256, 256, 0, stream>>>(batch, gptr);

    dim3 g1((NN + 127) / 128, 1);
    dim3 g2((NN + 127) / 128, 2);
    for (int i = 0; i < LL; ++i) {
        k_gemm<0><<<g1, 256, 0, stream>>>(h, conv_w + (size_t)i * HH * HH, nullptr, dinv, y,
                                          HH, HH);
        k_agg<<<(NN + 3) / 4, 256, 0, stream>>>(y, rowptr, col, dinv, conv_b + (size_t)i * HH,
                                                agg);
        k_stats<<<GG, 128, 0, stream>>>(agg, gptr, mean_scale + (size_t)i * HH, gmean, grstd);
        k_normswish<<<(NN * 32 + 255) / 256, 256, 0, stream>>>(
            agg, batch, gamma + (size_t)i * HH, beta + (size_t)i * HH,
            mean_scale + (size_t)i * HH, gmean, grstd, y);
        k_gemm<1><<<g2, 256, 0, stream>>>(y, mlp_w1 + (size_t)i * MM * HH,
                                          mlp_b1 + (size_t)i * MM, nullptr, t, HH, MM);
        k_gemm<2><<<g1, 256, 0, stream>>>(t, mlp_w2 + (size_t)i * HH * MM,
                                          mlp_b2 + (size_t)i * HH, h, h, MM, HH);
    }
}

// Round 2
// 1511.958 us; speedup vs baseline: 2.0981x; 2.0981x over previous
//
#include <hip/hip_runtime.h>

#define NN 100000
#define EE 1600000
#define HH 128
#define MM 256
#define LL 6
#define GG 512
#define SCAN_NB ((NN + 1023) / 1024)

typedef __attribute__((ext_vector_type(8))) short short8;
typedef __attribute__((ext_vector_type(4))) float floatx4;

__device__ __forceinline__ float swishf(float v) {
    return v / (1.0f + __expf(-v));
}

__device__ __forceinline__ unsigned short f2bf(float f) {
    unsigned u = __builtin_bit_cast(unsigned, f);
    unsigned r = u + 0x7FFFu + ((u >> 16) & 1u);
    return (unsigned short)(r >> 16);
}

__device__ __forceinline__ float2 bf2f2(unsigned u) {
    float2 r;
    r.x = __builtin_bit_cast(float, u << 16);
    r.y = __builtin_bit_cast(float, u & 0xFFFF0000u);
    return r;
}

// h[n,c] = z_embed[z[n],c] + sum_j x[n,1+j]*extra_w[c,j] + extra_b[c]; also bf16 copy
__global__ void k_embed(const float* __restrict__ x, const float* __restrict__ z_embed,
                        const float* __restrict__ ew, const float* __restrict__ eb,
                        float* __restrict__ h, unsigned short* __restrict__ hb) {
    int idx = blockIdx.x * blockDim.x + threadIdx.x;
    if (idx >= NN * 32) return;
    int n = idx >> 5;
    int c0 = (idx & 31) << 2;
    const float* xr = x + (size_t)n * 4;
    int z = (int)xr[0];
    float x1 = xr[1], x2 = xr[2], x3 = xr[3];
    const float* ze = z_embed + (size_t)z * HH + c0;
    float o[4];
#pragma unroll
    for (int j = 0; j < 4; ++j) {
        int c = c0 + j;
        o[j] = ze[j] + x1 * ew[c * 3 + 0] + x2 * ew[c * 3 + 1] + x3 * ew[c * 3 + 2] + eb[c];
    }
    *(float4*)(h + (size_t)n * HH + c0) = make_float4(o[0], o[1], o[2], o[3]);
    uint2 p;
    p.x = (unsigned)f2bf(o[0]) | ((unsigned)f2bf(o[1]) << 16);
    p.y = (unsigned)f2bf(o[2]) | ((unsigned)f2bf(o[3]) << 16);
    *(uint2*)(hb + (size_t)n * HH + c0) = p;
}

__global__ void k_f2bf(const float* __restrict__ src, unsigned short* __restrict__ dst, int n) {
    int i = blockIdx.x * blockDim.x + threadIdx.x;
    if (i < n) dst[i] = f2bf(src[i]);
}

__global__ void k_degree(const int* __restrict__ dst, int* __restrict__ deg) {
    int e = blockIdx.x * blockDim.x + threadIdx.x;
    if (e < EE) atomicAdd(&deg[dst[e]], 1);
}

__global__ void k_dinv(const int* __restrict__ deg, float* __restrict__ dinv) {
    int n = blockIdx.x * blockDim.x + threadIdx.x;
    if (n < NN) dinv[n] = rsqrtf((float)(deg[n] + 1));
}

__global__ void k_scan1(const int* __restrict__ deg, int* __restrict__ bsum) {
    __shared__ int sd[256];
    int t = threadIdx.x;
    int base = blockIdx.x * 1024 + t * 4;
    int s = 0;
#pragma unroll
    for (int j = 0; j < 4; ++j) {
        int i = base + j;
        if (i < NN) s += deg[i];
    }
    sd[t] = s;
    __syncthreads();
    for (int off = 128; off > 0; off >>= 1) {
        if (t < off) sd[t] += sd[t + off];
        __syncthreads();
    }
    if (t == 0) bsum[blockIdx.x] = sd[0];
}

__global__ void k_scan2(const int* __restrict__ bsum, int* __restrict__ boff) {
    __shared__ int sd[128];
    int t = threadIdx.x;
    int v = (t < SCAN_NB) ? bsum[t] : 0;
    sd[t] = v;
    __syncthreads();
    for (int off = 1; off < 128; off <<= 1) {
        int u = (t >= off) ? sd[t - off] : 0;
        __syncthreads();
        sd[t] += u;
        __syncthreads();
    }
    boff[t] = sd[t] - v;  // exclusive
}

__global__ void k_scan3(const int* __restrict__ deg, const int* __restrict__ boff,
                        int* __restrict__ rowptr) {
    __shared__ int sd[256];
    int t = threadIdx.x;
    int base = blockIdx.x * 1024 + t * 4;
    int v[4];
    int s = 0;
#pragma unroll
    for (int j = 0; j < 4; ++j) {
        int i = base + j;
        v[j] = (i < NN) ? deg[i] : 0;
        s += v[j];
    }
    sd[t] = s;
    __syncthreads();
    for (int off = 1; off < 256; off <<= 1) {
        int u = (t >= off) ? sd[t - off] : 0;
        __syncthreads();
        sd[t] += u;
        __syncthreads();
    }
    int run = boff[blockIdx.x] + sd[t] - s;
#pragma unroll
    for (int j = 0; j < 4; ++j) {
        int i = base + j;
        if (i < NN) rowptr[i] = run;
        if (i == NN - 1) rowptr[NN] = run + v[j];
        run += v[j];
    }
}

__global__ void k_fill(const int* __restrict__ ei, const int* __restrict__ rowptr,
                       int* __restrict__ cursor, int* __restrict__ col) {
    int e = blockIdx.x * blockDim.x + threadIdx.x;
    if (e >= EE) return;
    int s = ei[e];
    int d = ei[EE + e];
    int p = atomicAdd(&cursor[d], 1);
    col[rowptr[d] + p] = s;
}

__global__ void k_gptr(const int* __restrict__ batch, int* __restrict__ gptr) {
    int n = blockIdx.x * blockDim.x + threadIdx.x;
    if (n >= NN) return;
    int b = batch[n];
    int pb = (n == 0) ? -1 : batch[n - 1];
    for (int g = pb + 1; g <= b; ++g) gptr[g] = n;
    if (n == NN - 1) {
        for (int g = b + 1; g <= GG; ++g) gptr[g] = NN;
    }
}

// MFMA GEMM: C[N,Cout] = A[N,K](bf16) @ B[Cout,K](bf16)^T, fp32 accumulate.
// EPI 0: Cb = bf16(acc * dinv[r])                 (aux = dinv)
// EPI 1: Cb = bf16(swish(acc + bias))
// EPI 2: o = swish(acc + bias) + res[r,c]; Cf = o; Cb = bf16(o)   (aux = res fp32, Cout=HH)
template <int EPI>
__global__ __launch_bounds__(256) void k_gemm_mfma(const unsigned short* __restrict__ A,
                                                   const unsigned short* __restrict__ B,
                                                   const float* __restrict__ bias,
                                                   const float* aux, float* Cf,
                                                   unsigned short* __restrict__ Cb, int K,
                                                   int Cout) {
    __shared__ unsigned short As[128][72];
    __shared__ unsigned short Bs[128][72];
    const int tid = threadIdx.x;
    const int wave = tid >> 6;
    const int lane = tid & 63;
    const int quad = lane >> 4;
    const int l16 = lane & 15;
    const int wr = (wave & 1) << 6;
    const int wc = (wave >> 1) << 6;
    const int rowBase = blockIdx.x * 128;
    const int colBase = blockIdx.y * 128;

    floatx4 acc[4][4];
    const floatx4 zed = {0.f, 0.f, 0.f, 0.f};
#pragma unroll
    for (int i = 0; i < 4; ++i)
#pragma unroll
        for (int j = 0; j < 4; ++j) acc[i][j] = zed;

    const int srow = tid >> 3;        // 0..31
    const int skk = (tid & 7) << 3;   // 0,8,..,56

    for (int k0 = 0; k0 < K; k0 += 64) {
        __syncthreads();
#pragma unroll
        for (int p = 0; p < 4; ++p) {
            int rl = srow + (p << 5);
            int r = rowBase + rl;
            if (r >= NN) r = NN - 1;
            uint4 va = *(const uint4*)(A + (size_t)r * K + k0 + skk);
            *(uint4*)(&As[rl][skk]) = va;
            uint4 vb = *(const uint4*)(B + (size_t)(colBase + rl) * K + k0 + skk);
            *(uint4*)(&Bs[rl][skk]) = vb;
        }
        __syncthreads();
#pragma unroll
        for (int ks = 0; ks < 2; ++ks) {
            int koff = (ks << 5) + (quad << 3);
            short8 a[4], b[4];
#pragma unroll
            for (int i = 0; i < 4; ++i) a[i] = *(const short8*)(&As[wr + (i << 4) + l16][koff]);
#pragma unroll
            for (int j = 0; j < 4; ++j) b[j] = *(const short8*)(&Bs[wc + (j << 4) + l16][koff]);
#pragma unroll
            for (int i = 0; i < 4; ++i)
#pragma unroll
                for (int j = 0; j < 4; ++j)
                    acc[i][j] =
                        __builtin_amdgcn_mfma_f32_16x16x32_bf16(a[i], b[j], acc[i][j], 0, 0, 0);
        }
    }

    float bv[4];
    if (EPI >= 1) {
#pragma unroll
        for (int j = 0; j < 4; ++j) bv[j] = bias[colBase + wc + (j << 4) + l16];
    }
#pragma unroll
    for (int i = 0; i < 4; ++i) {
#pragma unroll
        for (int reg = 0; reg < 4; ++reg) {
            int r = rowBase + wr + (i << 4) + (quad << 2) + reg;
            if (r < NN) {
                if (EPI == 0) {
                    float dv = aux[r];
#pragma unroll
                    for (int j = 0; j < 4; ++j) {
                        int c = colBase + wc + (j << 4) + l16;
                        Cb[(size_t)r * Cout + c] = f2bf(acc[i][j][reg] * dv);
                    }
                } else if (EPI == 1) {
#pragma unroll
                    for (int j = 0; j < 4; ++j) {
                        int c = colBase + wc + (j << 4) + l16;
                        Cb[(size_t)r * Cout + c] = f2bf(swishf(acc[i][j][reg] + bv[j]));
                    }
                } else {
#pragma unroll
                    for (int j = 0; j < 4; ++j) {
                        int c = colBase + wc + (j << 4) + l16;
                        float o = swishf(acc[i][j][reg] + bv[j]) + aux[(size_t)r * HH + c];
                        Cf[(size_t)r * HH + c] = o;
                        Cb[(size_t)r * HH + c] = f2bf(o);
                    }
                }
            }
        }
    }
}

// agg[d] = dinv[d] * (sum_{s in in(d)} y[s] + y[d]) + conv_b   (y bf16, pre-scaled by dinv[src])
__global__ __launch_bounds__(256) void k_agg(const unsigned short* __restrict__ y,
                                             const int* __restrict__ rowptr,
                                             const int* __restrict__ col,
                                             const float* __restrict__ dinv,
                                             const float* __restrict__ cb,
                                             float* __restrict__ agg) {
    int w = threadIdx.x >> 6;
    int lane = threadIdx.x & 63;
    int d = blockIdx.x * 4 + w;
    if (d >= NN) return;
    int c = lane << 1;
    const unsigned* yv = (const unsigned*)y;  // index n*64 + lane -> 2 bf16
    float2 acc = bf2f2(yv[(size_t)d * 64 + lane]);
    int beg = rowptr[d];
    int end = rowptr[d + 1];
    int e = beg;
    for (; e + 3 < end; e += 4) {
        int s0 = col[e], s1 = col[e + 1], s2 = col[e + 2], s3 = col[e + 3];
        float2 v0 = bf2f2(yv[(size_t)s0 * 64 + lane]);
        float2 v1 = bf2f2(yv[(size_t)s1 * 64 + lane]);
        float2 v2 = bf2f2(yv[(size_t)s2 * 64 + lane]);
        float2 v3 = bf2f2(yv[(size_t)s3 * 64 + lane]);
        acc.x += (v0.x + v1.x) + (v2.x + v3.x);
        acc.y += (v0.y + v1.y) + (v2.y + v3.y);
    }
    for (; e < end; ++e) {
        float2 v0 = bf2f2(yv[(size_t)col[e] * 64 + lane]);
        acc.x += v0.x;
        acc.y += v0.y;
    }
    float dv = dinv[d];
    float2 outv;
    outv.x = acc.x * dv + cb[c];
    outv.y = acc.y * dv + cb[c + 1];
    *(float2*)(agg + (size_t)d * HH + c) = outv;
}

// per-graph mean/rstd; var = E[a^2] - ms*(2-ms)*mean^2
__global__ __launch_bounds__(512) void k_stats(const float* __restrict__ agg,
                                               const int* __restrict__ gptr,
                                               const float* __restrict__ ms,
                                               float* __restrict__ gmean,
                                               float* __restrict__ grstd) {
    __shared__ float s1[512];
    __shared__ float s2[512];
    int g = blockIdx.x;
    int t = threadIdx.x;
    int c = t & 127;
    int part = t >> 7;
    int beg = gptr[g];
    int end = gptr[g + 1];
    float S1 = 0.f, S2 = 0.f;
    for (int n = beg + part; n < end; n += 4) {
        float v = agg[(size_t)n * HH + c];
        S1 += v;
        S2 += v * v;
    }
    s1[t] = S1;
    s2[t] = S2;
    __syncthreads();
    if (part == 0) {
        S1 = (s1[c] + s1[c + 128]) + (s1[c + 256] + s1[c + 384]);
        S2 = (s2[c] + s2[c + 128]) + (s2[c + 256] + s2[c + 384]);
        int cnt = end - beg;
        float inv = 1.0f / (float)(cnt > 0 ? cnt : 1);
        float m = S1 * inv;
        float msc = ms[c];
        float var = S2 * inv - msc * (2.0f - msc) * m * m;
        gmean[g * HH + c] = m;
        grstd[g * HH + c] = rsqrtf(var + 1e-5f);
    }
}

__global__ void k_normswish(const float* __restrict__ agg, const int* __restrict__ batch,
                            const float* __restrict__ gamma, const float* __restrict__ beta,
                            const float* __restrict__ ms, const float* __restrict__ gmean,
                            const float* __restrict__ grstd, unsigned short* __restrict__ ha) {
    int idx = blockIdx.x * blockDim.x + threadIdx.x;
    if (idx >= NN * 32) return;
    int n = idx >> 5;
    int c0 = (idx & 31) << 2;
    int g = batch[n];
    float4 a = *(const float4*)(agg + (size_t)n * HH + c0);
    float av[4] = {a.x, a.y, a.z, a.w};
    unsigned short o[4];
#pragma unroll
    for (int j = 0; j < 4; ++j) {
        int c = c0 + j;
        float sub = av[j] - ms[c] * gmean[g * HH + c];
        float hn = gamma[c] * sub * grstd[g * HH + c] + beta[c];
        o[j] = f2bf(swishf(hn));
    }
    uint2 p;
    p.x = (unsigned)o[0] | ((unsigned)o[1] << 16);
    p.y = (unsigned)o[2] | ((unsigned)o[3] << 16);
    *(uint2*)(ha + (size_t)n * HH + c0) = p;
}

extern "C" void kernel_launch(void* const* d_in, const int* in_sizes, int n_in,
                              void* d_out, int out_size, void* d_ws, size_t ws_size,
                              hipStream_t stream) {
    const float* x = (const float*)d_in[0];
    const int* ei = (const int*)d_in[1];
    const int* batch = (const int*)d_in[2];
    const float* z_embed = (const float*)d_in[3];
    const float* extra_w = (const float*)d_in[4];
    const float* extra_b = (const float*)d_in[5];
    const float* conv_w = (const float*)d_in[6];
    const float* conv_b = (const float*)d_in[7];
    const float* gamma = (const float*)d_in[8];
    const float* beta = (const float*)d_in[9];
    const float* mean_scale = (const float*)d_in[10];
    const float* mlp_w1 = (const float*)d_in[11];
    const float* mlp_b1 = (const float*)d_in[12];
    const float* mlp_w2 = (const float*)d_in[13];
    const float* mlp_b2 = (const float*)d_in[14];
    float* h = (float*)d_out;

    char* wsB = (char*)d_ws;
    size_t off = 0;
    auto alloc = [&](size_t bytes) -> void* {
        void* p = (void*)(wsB + off);
        off = (off + bytes + 255) & ~(size_t)255;
        return p;
    };
    float* dinv = (float*)alloc((size_t)NN * 4);
    int* deg = (int*)alloc((size_t)NN * 4);
    int* cursor = (int*)alloc((size_t)NN * 4);
    int* rowptr = (int*)alloc((size_t)(NN + 1) * 4);
    int* bsum = (int*)alloc(128 * 4);
    int* boff = (int*)alloc(128 * 4);
    int* col = (int*)alloc((size_t)EE * 4);
    int* gptr = (int*)alloc((size_t)(GG + 1) * 4);
    float* gmean = (float*)alloc((size_t)GG * HH * 4);
    float* grstd = (float*)alloc((size_t)GG * HH * 4);
    // bf16 weights: conv_w | mlp_w1 | mlp_w2
    unsigned short* wb = (unsigned short*)alloc((size_t)(LL * (HH * HH + MM * HH + HH * MM)) * 2);
    unsigned short* cwb = wb;
    unsigned short* w1b = wb + (size_t)LL * HH * HH;
    unsigned short* w2b = w1b + (size_t)LL * MM * HH;
    unsigned short* hb = (unsigned short*)alloc((size_t)NN * HH * 2);   // bf16 h
    unsigned short* ybuf = (unsigned short*)alloc((size_t)NN * HH * 2); // y_bf, then ha_bf
    float* agg = (float*)alloc((size_t)NN * HH * 4);                    // fp32 agg; aliases t_bf
    unsigned short* tb = (unsigned short*)agg;                          // bf16 t [N, M]

    hipMemsetAsync(deg, 0, (size_t)NN * 4, stream);
    hipMemsetAsync(cursor, 0, (size_t)NN * 4, stream);

    k_embed<<<(NN * 32 + 255) / 256, 256, 0, stream>>>(x, z_embed, extra_w, extra_b, h, hb);
    {
        int n1 = LL * HH * HH, n2 = LL * MM * HH, n3 = LL * HH * MM;
        k_f2bf<<<(n1 + 255) / 256, 256, 0, stream>>>(conv_w, cwb, n1);
        k_f2bf<<<(n2 + 255) / 256, 256, 0, stream>>>(mlp_w1, w1b, n2);
        k_f2bf<<<(n3 + 255) / 256, 256, 0, stream>>>(mlp_w2, w2b, n3);
    }
    k_degree<<<(EE + 255) / 256, 256, 0, stream>>>(ei + EE, deg);
    k_dinv<<<(NN + 255) / 256, 256, 0, stream>>>(deg, dinv);
    k_scan1<<<SCAN_NB, 256, 0, stream>>>(deg, bsum);
    k_scan2<<<1, 128, 0, stream>>>(bsum, boff);
    k_scan3<<<SCAN_NB, 256, 0, stream>>>(deg, boff, rowptr);
    k_fill<<<(EE + 255) / 256, 256, 0, stream>>>(ei, rowptr, cursor, col);
    k_gptr<<<(NN + 255) / 256, 256, 0, stream>>>(batch, gptr);

    dim3 g1((NN + 127) / 128, 1);
    dim3 g2((NN + 127) / 128, 2);
    for (int i = 0; i < LL; ++i) {
        k_gemm_mfma<0><<<g1, 256, 0, stream>>>(hb, cwb + (size_t)i * HH * HH, nullptr, dinv,
                                               nullptr, ybuf, HH, HH);
        k_agg<<<(NN + 3) / 4, 256, 0, stream>>>(ybuf, rowptr, col, dinv,
                                                conv_b + (size_t)i * HH, agg);
        k_stats<<<GG, 512, 0, stream>>>(agg, gptr, mean_scale + (size_t)i * HH, gmean, grstd);
        k_normswish<<<(NN * 32 + 255) / 256, 256, 0, stream>>>(
            agg, batch, gamma + (size_t)i * HH, beta + (size_t)i * HH,
            mean_scale + (size_t)i * HH, gmean, grstd, ybuf);
        k_gemm_mfma<1><<<g2, 256, 0, stream>>>(ybuf, w1b + (size_t)i * MM * HH,
                                               mlp_b1 + (size_t)i * MM, nullptr, nullptr, tb,
                                               HH, MM);
        k_gemm_mfma<2><<<g1, 256, 0, stream>>>(tb, w2b + (size_t)i * HH * MM,
                                               mlp_b2 + (size_t)i * HH, h, h, hb, MM, HH);
    }
}

// Round 3
// 1428.977 us; speedup vs baseline: 2.2200x; 1.0581x over previous
//
#include <hip/hip_runtime.h>

#define NN 100000
#define EE 1600000
#define HH 128
#define MM 256
#define LL 6
#define GG 512
#define SCAN_NB ((NN + 1023) / 1024)

typedef __attribute__((ext_vector_type(8))) short short8;
typedef __attribute__((ext_vector_type(4))) float floatx4;

__device__ __forceinline__ float swishf(float v) {
    return v / (1.0f + __expf(-v));
}

__device__ __forceinline__ unsigned short f2bf(float f) {
    unsigned u = __builtin_bit_cast(unsigned, f);
    unsigned r = u + 0x7FFFu + ((u >> 16) & 1u);
    return (unsigned short)(r >> 16);
}

__device__ __forceinline__ float bf2f(unsigned short u) {
    return __builtin_bit_cast(float, (unsigned)u << 16);
}

__device__ __forceinline__ float2 bf2f2(unsigned u) {
    float2 r;
    r.x = __builtin_bit_cast(float, u << 16);
    r.y = __builtin_bit_cast(float, u & 0xFFFF0000u);
    return r;
}

// h[n,c] = z_embed[z[n],c] + sum_j x[n,1+j]*extra_w[c,j] + extra_b[c]  (bf16 out)
__global__ void k_embed(const float* __restrict__ x, const float* __restrict__ z_embed,
                        const float* __restrict__ ew, const float* __restrict__ eb,
                        unsigned short* __restrict__ hb) {
    int idx = blockIdx.x * blockDim.x + threadIdx.x;
    if (idx >= NN * 32) return;
    int n = idx >> 5;
    int c0 = (idx & 31) << 2;
    const float* xr = x + (size_t)n * 4;
    int z = (int)xr[0];
    float x1 = xr[1], x2 = xr[2], x3 = xr[3];
    const float* ze = z_embed + (size_t)z * HH + c0;
    float o[4];
#pragma unroll
    for (int j = 0; j < 4; ++j) {
        int c = c0 + j;
        o[j] = ze[j] + x1 * ew[c * 3 + 0] + x2 * ew[c * 3 + 1] + x3 * ew[c * 3 + 2] + eb[c];
    }
    uint2 p;
    p.x = (unsigned)f2bf(o[0]) | ((unsigned)f2bf(o[1]) << 16);
    p.y = (unsigned)f2bf(o[2]) | ((unsigned)f2bf(o[3]) << 16);
    *(uint2*)(hb + (size_t)n * HH + c0) = p;
}

// cast 3 weight tensors fp32->bf16 in one launch
__global__ void k_f2bf3(const float* __restrict__ s1, unsigned short* __restrict__ d1, int n1,
                        const float* __restrict__ s2, unsigned short* __restrict__ d2, int n2,
                        const float* __restrict__ s3, unsigned short* __restrict__ d3, int n3) {
    int i = blockIdx.x * blockDim.x + threadIdx.x;
    if (i < n1) {
        d1[i] = f2bf(s1[i]);
    } else if (i < n1 + n2) {
        d2[i - n1] = f2bf(s2[i - n1]);
    } else if (i < n1 + n2 + n3) {
        d3[i - n1 - n2] = f2bf(s3[i - n1 - n2]);
    }
}

// XCD-partitioned degree count: partition by contiguous dst range so each
// partition's deg lines stay in one XCD's L2.
__global__ __launch_bounds__(256) void k_degree_p(const int* __restrict__ dst,
                                                  int* __restrict__ deg) {
    int part = blockIdx.x & 7;
    int blk = blockIdx.x >> 3;
    int nb = gridDim.x >> 3;
    int lo = (int)((long long)part * NN / 8);
    int hi = (int)((long long)(part + 1) * NN / 8);
    for (int e = blk * 256 + threadIdx.x; e < EE; e += nb * 256) {
        int d = dst[e];
        if (d >= lo && d < hi) atomicAdd(&deg[d], 1);
    }
}

__global__ void k_dinv(const int* __restrict__ deg, float* __restrict__ dinv) {
    int n = blockIdx.x * blockDim.x + threadIdx.x;
    if (n < NN) dinv[n] = rsqrtf((float)(deg[n] + 1));
}

__global__ void k_scan1(const int* __restrict__ deg, int* __restrict__ bsum) {
    __shared__ int sd[256];
    int t = threadIdx.x;
    int base = blockIdx.x * 1024 + t * 4;
    int s = 0;
#pragma unroll
    for (int j = 0; j < 4; ++j) {
        int i = base + j;
        if (i < NN) s += deg[i];
    }
    sd[t] = s;
    __syncthreads();
    for (int off = 128; off > 0; off >>= 1) {
        if (t < off) sd[t] += sd[t + off];
        __syncthreads();
    }
    if (t == 0) bsum[blockIdx.x] = sd[0];
}

__global__ void k_scan2(const int* __restrict__ bsum, int* __restrict__ boff) {
    __shared__ int sd[128];
    int t = threadIdx.x;
    int v = (t < SCAN_NB) ? bsum[t] : 0;
    sd[t] = v;
    __syncthreads();
    for (int off = 1; off < 128; off <<= 1) {
        int u = (t >= off) ? sd[t - off] : 0;
        __syncthreads();
        sd[t] += u;
        __syncthreads();
    }
    boff[t] = sd[t] - v;  // exclusive
}

__global__ void k_scan3(const int* __restrict__ deg, const int* __restrict__ boff,
                        int* __restrict__ rowptr) {
    __shared__ int sd[256];
    int t = threadIdx.x;
    int base = blockIdx.x * 1024 + t * 4;
    int v[4];
    int s = 0;
#pragma unroll
    for (int j = 0; j < 4; ++j) {
        int i = base + j;
        v[j] = (i < NN) ? deg[i] : 0;
        s += v[j];
    }
    sd[t] = s;
    __syncthreads();
    for (int off = 1; off < 256; off <<= 1) {
        int u = (t >= off) ? sd[t - off] : 0;
        __syncthreads();
        sd[t] += u;
        __syncthreads();
    }
    int run = boff[blockIdx.x] + sd[t] - s;
#pragma unroll
    for (int j = 0; j < 4; ++j) {
        int i = base + j;
        if (i < NN) rowptr[i] = run;
        if (i == NN - 1) rowptr[NN] = run + v[j];
        run += v[j];
    }
}

// XCD-partitioned CSR fill: col/cursor/rowptr slices for one contiguous dst
// range stay resident in a single XCD's L2 -> col lines written back once.
__global__ __launch_bounds__(256) void k_fill_p(const int* __restrict__ ei,
                                                const int* __restrict__ rowptr,
                                                int* __restrict__ cursor,
                                                int* __restrict__ col) {
    int part = blockIdx.x & 7;
    int blk = blockIdx.x >> 3;
    int nb = gridDim.x >> 3;
    int lo = (int)((long long)part * NN / 8);
    int hi = (int)((long long)(part + 1) * NN / 8);
    for (int e = blk * 256 + threadIdx.x; e < EE; e += nb * 256) {
        int d = ei[EE + e];
        if (d >= lo && d < hi) {
            int p = atomicAdd(&cursor[d], 1);
            col[rowptr[d] + p] = ei[e];
        }
    }
}

__global__ void k_gptr(const int* __restrict__ batch, int* __restrict__ gptr) {
    int n = blockIdx.x * blockDim.x + threadIdx.x;
    if (n >= NN) return;
    int b = batch[n];
    int pb = (n == 0) ? -1 : batch[n - 1];
    for (int g = pb + 1; g <= b; ++g) gptr[g] = n;
    if (n == NN - 1) {
        for (int g = b + 1; g <= GG; ++g) gptr[g] = NN;
    }
}

// MFMA GEMM: C[N,Cout] = A[N,K](bf16) @ B[Cout,K](bf16)^T, fp32 accumulate.
// EPI 0: Cb = bf16(acc * dinv[r])                 (aux = dinv fp32)
// EPI 1: Cb = bf16(swish(acc + bias))
// EPI 2: o = swish(acc + bias) + res_bf16[r,c]; Cb = bf16(o); if(writeF) Cf = o
template <int EPI>
__global__ __launch_bounds__(256) void k_gemm_mfma(const unsigned short* __restrict__ A,
                                                   const unsigned short* __restrict__ B,
                                                   const float* __restrict__ bias,
                                                   const void* aux, float* Cf,
                                                   unsigned short* __restrict__ Cb, int K,
                                                   int Cout, int writeF) {
    __shared__ unsigned short As[128][72];
    __shared__ unsigned short Bs[128][72];
    const int tid = threadIdx.x;
    const int wave = tid >> 6;
    const int lane = tid & 63;
    const int quad = lane >> 4;
    const int l16 = lane & 15;
    const int wr = (wave & 1) << 6;
    const int wc = (wave >> 1) << 6;
    const int rowBase = blockIdx.x * 128;
    const int colBase = blockIdx.y * 128;

    floatx4 acc[4][4];
    const floatx4 zed = {0.f, 0.f, 0.f, 0.f};
#pragma unroll
    for (int i = 0; i < 4; ++i)
#pragma unroll
        for (int j = 0; j < 4; ++j) acc[i][j] = zed;

    const int srow = tid >> 3;       // 0..31
    const int skk = (tid & 7) << 3;  // 0,8,..,56

    for (int k0 = 0; k0 < K; k0 += 64) {
        __syncthreads();
#pragma unroll
        for (int p = 0; p < 4; ++p) {
            int rl = srow + (p << 5);
            int r = rowBase + rl;
            if (r >= NN) r = NN - 1;
            uint4 va = *(const uint4*)(A + (size_t)r * K + k0 + skk);
            *(uint4*)(&As[rl][skk]) = va;
            uint4 vb = *(const uint4*)(B + (size_t)(colBase + rl) * K + k0 + skk);
            *(uint4*)(&Bs[rl][skk]) = vb;
        }
        __syncthreads();
#pragma unroll
        for (int ks = 0; ks < 2; ++ks) {
            int koff = (ks << 5) + (quad << 3);
            short8 a[4], b[4];
#pragma unroll
            for (int i = 0; i < 4; ++i) a[i] = *(const short8*)(&As[wr + (i << 4) + l16][koff]);
#pragma unroll
            for (int j = 0; j < 4; ++j) b[j] = *(const short8*)(&Bs[wc + (j << 4) + l16][koff]);
#pragma unroll
            for (int i = 0; i < 4; ++i)
#pragma unroll
                for (int j = 0; j < 4; ++j)
                    acc[i][j] =
                        __builtin_amdgcn_mfma_f32_16x16x32_bf16(a[i], b[j], acc[i][j], 0, 0, 0);
        }
    }

    float bv[4];
    if (EPI >= 1) {
#pragma unroll
        for (int j = 0; j < 4; ++j) bv[j] = bias[colBase + wc + (j << 4) + l16];
    }
#pragma unroll
    for (int i = 0; i < 4; ++i) {
#pragma unroll
        for (int reg = 0; reg < 4; ++reg) {
            int r = rowBase + wr + (i << 4) + (quad << 2) + reg;
            if (r < NN) {
                if (EPI == 0) {
                    float dv = ((const float*)aux)[r];
#pragma unroll
                    for (int j = 0; j < 4; ++j) {
                        int c = colBase + wc + (j << 4) + l16;
                        Cb[(size_t)r * Cout + c] = f2bf(acc[i][j][reg] * dv);
                    }
                } else if (EPI == 1) {
#pragma unroll
                    for (int j = 0; j < 4; ++j) {
                        int c = colBase + wc + (j << 4) + l16;
                        Cb[(size_t)r * Cout + c] = f2bf(swishf(acc[i][j][reg] + bv[j]));
                    }
                } else {
                    const unsigned short* res = (const unsigned short*)aux;
#pragma unroll
                    for (int j = 0; j < 4; ++j) {
                        int c = colBase + wc + (j << 4) + l16;
                        float o = swishf(acc[i][j][reg] + bv[j]) + bf2f(res[(size_t)r * HH + c]);
                        Cb[(size_t)r * HH + c] = f2bf(o);
                        if (writeF) Cf[(size_t)r * HH + c] = o;
                    }
                }
            }
        }
    }
}

// agg[d] = bf16( dinv[d] * (sum_{s in in(d)} y[s] + y[d]) + conv_b )   (y bf16)
__global__ __launch_bounds__(256) void k_agg(const unsigned short* __restrict__ y,
                                             const int* __restrict__ rowptr,
                                             const int* __restrict__ col,
                                             const float* __restrict__ dinv,
                                             const float* __restrict__ cb,
                                             unsigned short* __restrict__ agg) {
    int w = threadIdx.x >> 6;
    int lane = threadIdx.x & 63;
    int d = blockIdx.x * 4 + w;
    if (d >= NN) return;
    int c = lane << 1;
    const unsigned* yv = (const unsigned*)y;  // index n*64 + lane -> 2 bf16
    float2 acc = bf2f2(yv[(size_t)d * 64 + lane]);
    int beg = rowptr[d];
    int end = rowptr[d + 1];
    int e = beg;
    for (; e + 7 < end; e += 8) {
        int s[8];
#pragma unroll
        for (int q = 0; q < 8; ++q) s[q] = col[e + q];
        float2 v[8];
#pragma unroll
        for (int q = 0; q < 8; ++q) v[q] = bf2f2(yv[(size_t)s[q] * 64 + lane]);
#pragma unroll
        for (int q = 0; q < 8; ++q) {
            acc.x += v[q].x;
            acc.y += v[q].y;
        }
    }
    for (; e < end; ++e) {
        float2 v0 = bf2f2(yv[(size_t)col[e] * 64 + lane]);
        acc.x += v0.x;
        acc.y += v0.y;
    }
    float dv = dinv[d];
    float ox = acc.x * dv + cb[c];
    float oy = acc.y * dv + cb[c + 1];
    unsigned pk = (unsigned)f2bf(ox) | ((unsigned)f2bf(oy) << 16);
    ((unsigned*)agg)[(size_t)d * 64 + lane] = pk;
}

// per-graph mean/rstd from bf16 agg; var = E[a^2] - ms*(2-ms)*mean^2
__global__ __launch_bounds__(512) void k_stats(const unsigned short* __restrict__ agg,
                                               const int* __restrict__ gptr,
                                               const float* __restrict__ ms,
                                               float* __restrict__ gmean,
                                               float* __restrict__ grstd) {
    __shared__ float s1[512];
    __shared__ float s2[512];
    int g = blockIdx.x;
    int t = threadIdx.x;
    int c = t & 127;
    int part = t >> 7;
    int beg = gptr[g];
    int end = gptr[g + 1];
    float S1 = 0.f, S2 = 0.f;
    for (int n = beg + part; n < end; n += 4) {
        float v = bf2f(agg[(size_t)n * HH + c]);
        S1 += v;
        S2 += v * v;
    }
    s1[t] = S1;
    s2[t] = S2;
    __syncthreads();
    if (part == 0) {
        S1 = (s1[c] + s1[c + 128]) + (s1[c + 256] + s1[c + 384]);
        S2 = (s2[c] + s2[c + 128]) + (s2[c + 256] + s2[c + 384]);
        int cnt = end - beg;
        float inv = 1.0f / (float)(cnt > 0 ? cnt : 1);
        float m = S1 * inv;
        float msc = ms[c];
        float var = S2 * inv - msc * (2.0f - msc) * m * m;
        gmean[g * HH + c] = m;
        grstd[g * HH + c] = rsqrtf(var + 1e-5f);
    }
}

__global__ void k_normswish(const unsigned short* __restrict__ agg,
                            const int* __restrict__ batch, const float* __restrict__ gamma,
                            const float* __restrict__ beta, const float* __restrict__ ms,
                            const float* __restrict__ gmean, const float* __restrict__ grstd,
                            unsigned short* __restrict__ ha) {
    int idx = blockIdx.x * blockDim.x + threadIdx.x;
    if (idx >= NN * 32) return;
    int n = idx >> 5;
    int c0 = (idx & 31) << 2;
    int g = batch[n];
    uint2 ain = *(const uint2*)(agg + (size_t)n * HH + c0);
    float2 a01 = bf2f2(ain.x);
    float2 a23 = bf2f2(ain.y);
    float av[4] = {a01.x, a01.y, a23.x, a23.y};
    unsigned short o[4];
#pragma unroll
    for (int j = 0; j < 4; ++j) {
        int c = c0 + j;
        float sub = av[j] - ms[c] * gmean[g * HH + c];
        float hn = gamma[c] * sub * grstd[g * HH + c] + beta[c];
        o[j] = f2bf(swishf(hn));
    }
    uint2 p;
    p.x = (unsigned)o[0] | ((unsigned)o[1] << 16);
    p.y = (unsigned)o[2] | ((unsigned)o[3] << 16);
    *(uint2*)(ha + (size_t)n * HH + c0) = p;
}

extern "C" void kernel_launch(void* const* d_in, const int* in_sizes, int n_in,
                              void* d_out, int out_size, void* d_ws, size_t ws_size,
                              hipStream_t stream) {
    const float* x = (const float*)d_in[0];
    const int* ei = (const int*)d_in[1];
    const int* batch = (const int*)d_in[2];
    const float* z_embed = (const float*)d_in[3];
    const float* extra_w = (const float*)d_in[4];
    const float* extra_b = (const float*)d_in[5];
    const float* conv_w = (const float*)d_in[6];
    const float* conv_b = (const float*)d_in[7];
    const float* gamma = (const float*)d_in[8];
    const float* beta = (const float*)d_in[9];
    const float* mean_scale = (const float*)d_in[10];
    const float* mlp_w1 = (const float*)d_in[11];
    const float* mlp_b1 = (const float*)d_in[12];
    const float* mlp_w2 = (const float*)d_in[13];
    const float* mlp_b2 = (const float*)d_in[14];
    float* h_out = (float*)d_out;

    char* wsB = (char*)d_ws;
    size_t off = 0;
    auto alloc = [&](size_t bytes) -> void* {
        void* p = (void*)(wsB + off);
        off = (off + bytes + 255) & ~(size_t)255;
        return p;
    };
    float* dinv = (float*)alloc((size_t)NN * 4);
    int* deg = (int*)alloc((size_t)NN * 4);
    int* cursor = (int*)alloc((size_t)NN * 4);
    int* rowptr = (int*)alloc((size_t)(NN + 1) * 4);
    int* bsum = (int*)alloc(128 * 4);
    int* boff = (int*)alloc(128 * 4);
    int* col = (int*)alloc((size_t)EE * 4);
    int* gptr = (int*)alloc((size_t)(GG + 1) * 4);
    float* gmean = (float*)alloc((size_t)GG * HH * 4);
    float* grstd = (float*)alloc((size_t)GG * HH * 4);
    // bf16 weights: conv_w | mlp_w1 | mlp_w2
    unsigned short* wb =
        (unsigned short*)alloc((size_t)(LL * (HH * HH + MM * HH + HH * MM)) * 2);
    unsigned short* cwb = wb;
    unsigned short* w1b = wb + (size_t)LL * HH * HH;
    unsigned short* w2b = w1b + (size_t)LL * MM * HH;
    unsigned short* hb = (unsigned short*)alloc((size_t)NN * HH * 2);    // bf16 h (residual)
    unsigned short* ybuf = (unsigned short*)alloc((size_t)NN * HH * 2);  // y_bf then ha_bf
    unsigned short* tb = (unsigned short*)alloc((size_t)NN * MM * 2);    // t bf16; aliases agg
    unsigned short* aggb = tb;  // agg bf16 [N,H] (consumed before t is written)

    hipMemsetAsync(deg, 0, (size_t)NN * 4, stream);
    hipMemsetAsync(cursor, 0, (size_t)NN * 4, stream);

    k_embed<<<(NN * 32 + 255) / 256, 256, 0, stream>>>(x, z_embed, extra_w, extra_b, hb);
    {
        int n1 = LL * HH * HH, n2 = LL * MM * HH, n3 = LL * HH * MM;
        int nt = n1 + n2 + n3;
        k_f2bf3<<<(nt + 255) / 256, 256, 0, stream>>>(conv_w, cwb, n1, mlp_w1, w1b, n2,
                                                      mlp_w2, w2b, n3);
    }
    k_degree_p<<<1024, 256, 0, stream>>>(ei + EE, deg);
    k_dinv<<<(NN + 255) / 256, 256, 0, stream>>>(deg, dinv);
    k_scan1<<<SCAN_NB, 256, 0, stream>>>(deg, bsum);
    k_scan2<<<1, 128, 0, stream>>>(bsum, boff);
    k_scan3<<<SCAN_NB, 256, 0, stream>>>(deg, boff, rowptr);
    k_fill_p<<<1024, 256, 0, stream>>>(ei, rowptr, cursor, col);
    k_gptr<<<(NN + 255) / 256, 256, 0, stream>>>(batch, gptr);

    dim3 g1((NN + 127) / 128, 1);
    dim3 g2((NN + 127) / 128, 2);
    for (int i = 0; i < LL; ++i) {
        k_gemm_mfma<0><<<g1, 256, 0, stream>>>(hb, cwb + (size_t)i * HH * HH, nullptr, dinv,
                                               nullptr, ybuf, HH, HH, 0);
        k_agg<<<(NN + 3) / 4, 256, 0, stream>>>(ybuf, rowptr, col, dinv,
                                                conv_b + (size_t)i * HH, aggb);
        k_stats<<<GG, 512, 0, stream>>>(aggb, gptr, mean_scale + (size_t)i * HH, gmean, grstd);
        k_normswish<<<(NN * 32 + 255) / 256, 256, 0, stream>>>(
            aggb, batch, gamma + (size_t)i * HH, beta + (size_t)i * HH,
            mean_scale + (size_t)i * HH, gmean, grstd, ybuf);
        k_gemm_mfma<1><<<g2, 256, 0, stream>>>(ybuf, w1b + (size_t)i * MM * HH,
                                               mlp_b1 + (size_t)i * MM, nullptr, nullptr, tb,
                                               HH, MM, 0);
        k_gemm_mfma<2><<<g1, 256, 0, stream>>>(tb, w2b + (size_t)i * HH * MM,
                                               mlp_b2 + (size_t)i * HH, hb, h_out, hb, MM, HH,
                                               i == LL - 1 ? 1 : 0);
    }
}